// Round 1
// baseline (1352.126 us; speedup 1.0000x reference)
//
#include <hip/hip_runtime.h>

#define NQ 512
#define NC 128
#define EC 32
#define OC 64

__device__ __forceinline__ float silu_f(float x) {
    return x / (1.0f + __expf(-x));
}

// ---------------------------------------------------------------------------
// Prepass: decode virtual_mask (unknown upload layout: u8 / int32 / f32) into
// int32. Detection: count nonzero bytes at aligned (idx%4==0) vs non-aligned
// positions within the first n bytes.  u8: both >0.  int32 (0/1): aligned>0,
// nonaligned==0.  f32 (0.0/1.0): aligned==0 (low mantissa byte), nonaligned>0.
// vm has ~10% ones over 2048 elems -> detection is statistically certain.
// ---------------------------------------------------------------------------
__global__ void decode_mask_kernel(const unsigned char* __restrict__ raw,
                                   int* __restrict__ out, int n) {
    __shared__ int cntA, cntN;
    int t = threadIdx.x;
    if (t == 0) { cntA = 0; cntN = 0; }
    __syncthreads();
    int la = 0, ln = 0;
    for (int idx = t; idx < n; idx += blockDim.x) {
        unsigned char v = raw[idx];
        if (v) { if ((idx & 3) == 0) la++; else ln++; }
    }
    if (la) atomicAdd(&cntA, la);
    if (ln) atomicAdd(&cntN, ln);
    __syncthreads();
    int a = cntA, nn = cntN;
    for (int i = t; i < n; i += blockDim.x) {
        int v;
        if (a > 0 && nn == 0)      v = ((const int*)raw)[i];            // int32
        else if (a == 0)           v = (((const float*)raw)[i] != 0.0f); // f32
        else                       v = (raw[i] != 0);                    // u8
        out[i] = v;
    }
}

// ---------------------------------------------------------------------------
// Node path: one block per (b,i), 128 threads.
// Computes x_in, x_out (masked mean over row/col of edge), h, n (stored to ws),
// and node_logit (LN + silu + GEMV) directly to output.
// ---------------------------------------------------------------------------
__global__ __launch_bounds__(128) void node_kernel(
    const float* __restrict__ node, const float* __restrict__ edge,
    const int* __restrict__ block_id, const int* __restrict__ vmd,
    const float* __restrict__ W_nt, const float* __restrict__ b_nt,
    const float* __restrict__ W_n1, const float* __restrict__ b_n1,
    const float* __restrict__ W_no1, const float* __restrict__ b_no1,
    const float* __restrict__ g_no, const float* __restrict__ be_no,
    const float* __restrict__ W_no2, const float* __restrict__ b_no2,
    float* __restrict__ n_ws, float* __restrict__ out_node) {
    const int bi = blockIdx.x;
    const int b = bi >> 9, i = bi & (NQ - 1);
    const int t = threadIdx.x;

    __shared__ int   sid[NQ];
    __shared__ int   svm[NQ];
    __shared__ float xcat[192];
    __shared__ float rin[4][32];
    __shared__ float rout[4][32];
    __shared__ int   rcin[4], rcout[4];
    __shared__ float hbuf[128];
    __shared__ float red[128];
    __shared__ float zbuf[128];

    for (int k = t; k < NQ; k += 128) {
        sid[k] = block_id[b * NQ + k];
        svm[k] = vmd[b * NQ + k];
    }
    __syncthreads();

    const int  id_i = sid[i];
    const int  vm_i = svm[i];
    const bool nm_i = (id_i >= 0);

    const int c = t & 31, g = t >> 5;
    float accin = 0.f, accout = 0.f;
    int   cntin = 0, cntout = 0;
    const float* erow = edge + ((size_t)(b * NQ + i)) * NQ * EC; // edge[b,i,j,c]
    const float* ecol = edge + ((size_t)b * NQ * NQ + i) * EC;   // edge[b,j,i,c]
    for (int j = g; j < NQ; j += 4) {
        int  id_j = sid[j];
        bool nm_j = (id_j >= 0);
        bool pv = nm_i && nm_j;
        bool cin  = pv && ((id_i > id_j) || (id_i == id_j && !vm_i));
        bool cout = pv && ((id_j > id_i) || (id_j == id_i && !svm[j]));
        if (cin)  { accin  += erow[j * EC + c]; cntin++; }
        if (cout) { accout += ecol[(size_t)j * NQ * EC + c]; cntout++; }
    }
    rin[g][c] = accin;
    rout[g][c] = accout;
    if (c == 0) { rcin[g] = cntin; rcout[g] = cntout; }
    __syncthreads();

    if (t < 32) {
        float s = rin[0][t] + rin[1][t] + rin[2][t] + rin[3][t];
        float cnt = (float)(rcin[0] + rcin[1] + rcin[2] + rcin[3]);
        xcat[t] = s / fmaxf(cnt, 1.0f);
    } else if (t < 64) {
        int tc = t - 32;
        float s = rout[0][tc] + rout[1][tc] + rout[2][tc] + rout[3][tc];
        float cnt = (float)(rcout[0] + rcout[1] + rcout[2] + rcout[3]);
        xcat[t] = s / fmaxf(cnt, 1.0f);
    }
    {
        float nv = node[(size_t)(b * NQ + i) * NC + t];
        xcat[64 + t] = nm_i ? nv : 0.0f;
    }
    __syncthreads();

    // h = silu(xcat @ W_nt + b_nt) * nm
    float acc = b_nt[t];
    #pragma unroll 4
    for (int k = 0; k < 192; ++k) acc += xcat[k] * W_nt[k * NC + t];
    float h = nm_i ? silu_f(acc) : 0.0f;
    hbuf[t] = h;
    __syncthreads();

    // n = h @ W_n1 + b_n1 ; u = h @ W_no1 + b_no1
    float accn = b_n1[t];
    float u = b_no1[t];
    #pragma unroll 4
    for (int k = 0; k < 128; ++k) {
        float hk = hbuf[k];
        accn += hk * W_n1[k * 128 + t];
        u    += hk * W_no1[k * 128 + t];
    }
    n_ws[(size_t)(b * NQ + i) * 128 + t] = accn;

    // LayerNorm over 128 channels (across threads)
    red[t] = u;
    __syncthreads();
    for (int s = 64; s > 0; s >>= 1) { if (t < s) red[t] += red[t + s]; __syncthreads(); }
    float m = red[0] * (1.0f / 128.0f);
    __syncthreads();
    float d = u - m;
    red[t] = d * d;
    __syncthreads();
    for (int s = 64; s > 0; s >>= 1) { if (t < s) red[t] += red[t + s]; __syncthreads(); }
    float var = red[0] * (1.0f / 128.0f);
    float z = silu_f(d * rsqrtf(var + 1e-5f) * g_no[t] + be_no[t]);
    zbuf[t] = z;
    __syncthreads();

    if (t < 10) {
        float o = b_no2[t];
        #pragma unroll 4
        for (int k2 = 0; k2 < 128; ++k2) o += zbuf[k2] * W_no2[k2 * 10 + t];
        out_node[(size_t)(b * NQ + i) * 10 + t] = nm_i ? o : 0.0f;
    }
}

// ---------------------------------------------------------------------------
// Edge path. lane = unordered pair {i,j}. Weights consumed via wave-uniform
// loads (s_load -> SGPR operand in v_fmac). Per-lane intermediate vectors are
// parked in a private LDS row (stride 65 floats, bank-conflict free) whenever
// runtime-k indexing is needed.
// Pair enumeration: (i, (i+dj)&511) for dj in [0,256]; dj==256 valid only for
// i<256. Covers each unordered pair (incl. diagonal) exactly once.
// ---------------------------------------------------------------------------

template <int K, int C>
__device__ __forceinline__ void gemv_lds(const float* __restrict__ W,
                                         const float* lrow, float* acc) {
    #pragma unroll 1
    for (int kb = 0; kb < K / 8; ++kb) {
        float in[8];
        #pragma unroll
        for (int u = 0; u < 8; ++u) in[u] = lrow[kb * 8 + u];
        #pragma unroll
        for (int u = 0; u < 8; ++u) {
            const float* wr = W + (size_t)(kb * 8 + u) * C;
            #pragma unroll
            for (int cc = 0; cc < C; ++cc) acc[cc] += in[u] * wr[cc];
        }
    }
}

// K=32 GEMV with input straight from global (edge row, contiguous 128B)
__device__ __forceinline__ void gemv_edge(const float* __restrict__ W,
                                          const float* __restrict__ ev, float* acc) {
    #pragma unroll 1
    for (int kb = 0; kb < 4; ++kb) {
        float in[8];
        #pragma unroll
        for (int u = 0; u < 8; ++u) in[u] = ev[kb * 8 + u];
        #pragma unroll
        for (int u = 0; u < 8; ++u) {
            const float* wr = W + (size_t)(kb * 8 + u) * OC;
            #pragma unroll
            for (int cc = 0; cc < OC; ++cc) acc[cc] += in[u] * wr[cc];
        }
    }
}

// K=64 GEMV with input = v1[k] + v2[k] loaded from global on the fly
__device__ __forceinline__ void gemv_npair(const float* __restrict__ W,
                                           const float* __restrict__ v1,
                                           const float* __restrict__ v2, float* acc) {
    #pragma unroll 1
    for (int kb = 0; kb < 8; ++kb) {
        float in[8];
        #pragma unroll
        for (int u = 0; u < 8; ++u) in[u] = v1[kb * 8 + u] + v2[kb * 8 + u];
        #pragma unroll
        for (int u = 0; u < 8; ++u) {
            const float* wr = W + (size_t)(kb * 8 + u) * OC;
            #pragma unroll
            for (int cc = 0; cc < OC; ++cc) acc[cc] += in[u] * wr[cc];
        }
    }
}

__global__ __launch_bounds__(128) void edge_kernel(
    const float* __restrict__ edge, const int* __restrict__ block_id,
    const int* __restrict__ vmd, const float* __restrict__ n_ws,
    const float* __restrict__ W_e1, const float* __restrict__ b_e1,
    const float* __restrict__ W_f1, const float* __restrict__ b_f1,
    const float* __restrict__ W_f2, const float* __restrict__ b_f2,
    const float* __restrict__ W_eo1, const float* __restrict__ b_eo1,
    const float* __restrict__ g_eo, const float* __restrict__ be_eo,
    const float* __restrict__ W_eo2, const float* __restrict__ b_eo2,
    float* __restrict__ out_edge) {
    __shared__ float sbuf[128 * 65];
    float* lrow = sbuf + threadIdx.x * 65;

    const int P = blockIdx.x * 128 + threadIdx.x;
    const int b = P / (NQ * 257);
    int r = P - b * (NQ * 257);
    const int i = r / 257;
    const int dj = r - i * 257;
    const int j = (i + dj) & (NQ - 1);
    const bool valid = (dj != 256) || (i < 256);

    const int  id_i = block_id[b * NQ + i], id_j = block_id[b * NQ + j];
    const int  vm_i = vmd[b * NQ + i],      vm_j = vmd[b * NQ + j];
    const bool nm_i = (id_i >= 0), nm_j = (id_j >= 0);
    const bool em = nm_i && nm_j && ((id_i != id_j) || (!vm_i) || (!vm_j));

    const float* eij = edge + (((size_t)(b * NQ) + i) * NQ + j) * EC;
    const float* eji = edge + (((size_t)(b * NQ) + j) * NQ + i) * EC;
    const float* ni = n_ws + (size_t)(b * NQ + i) * 128; // n1[b,i]=ni[0:64], n2[b,i]=ni[64:128]
    const float* nj = n_ws + (size_t)(b * NQ + j) * 128;

    float ea[OC], eb[OC];

    // ---------------- direction a: (i,j) ----------------
    {
        float acc[OC];
        #pragma unroll
        for (int cc = 0; cc < OC; ++cc) acc[cc] = b_e1[cc];
        gemv_edge(W_e1, eij, acc);
        #pragma unroll
        for (int cc = 0; cc < OC; ++cc) lrow[cc] = acc[cc];   // park e0a
    }
    {
        float t1[OC], t2[OC];
        #pragma unroll
        for (int cc = 0; cc < OC; ++cc) t1[cc] = b_f1[cc];
        gemv_npair(W_f1, nj, ni + 64, t1);                     // npair_a = n1[b,j]+n2[b,i]
        #pragma unroll
        for (int cc = 0; cc < OC; ++cc) t1[cc] = silu_f(t1[cc]);
        #pragma unroll
        for (int cc = 0; cc < OC; ++cc) t2[cc] = b_f2[cc];
        gemv_lds<64, OC>(W_f2, lrow, t2);                      // e0a @ W_f2
        #pragma unroll
        for (int cc = 0; cc < OC; ++cc) t2[cc] = silu_f(t2[cc]);
        #pragma unroll 1
        for (int cb = 0; cb < 8; ++cb) {
            #pragma unroll
            for (int u = 0; u < 8; ++u) {
                int cc = cb * 8 + u;
                float np = nj[cc] + ni[64 + cc];
                float e0 = lrow[cc];
                ea[cc] = silu_f(np + e0 + t1[cc] * t2[cc]);
            }
        }
    }

    // ---------------- direction b: (j,i) ----------------
    {
        float acc[OC];
        #pragma unroll
        for (int cc = 0; cc < OC; ++cc) acc[cc] = b_e1[cc];
        gemv_edge(W_e1, eji, acc);
        #pragma unroll
        for (int cc = 0; cc < OC; ++cc) lrow[cc] = acc[cc];   // park e0b
    }
    {
        float t1[OC], t2[OC];
        #pragma unroll
        for (int cc = 0; cc < OC; ++cc) t1[cc] = b_f1[cc];
        gemv_npair(W_f1, ni, nj + 64, t1);                     // npair_b = n1[b,i]+n2[b,j]
        #pragma unroll
        for (int cc = 0; cc < OC; ++cc) t1[cc] = silu_f(t1[cc]);
        #pragma unroll
        for (int cc = 0; cc < OC; ++cc) t2[cc] = b_f2[cc];
        gemv_lds<64, OC>(W_f2, lrow, t2);
        #pragma unroll
        for (int cc = 0; cc < OC; ++cc) t2[cc] = silu_f(t2[cc]);
        #pragma unroll 1
        for (int cb = 0; cb < 8; ++cb) {
            #pragma unroll
            for (int u = 0; u < 8; ++u) {
                int cc = cb * 8 + u;
                float np = ni[cc] + nj[64 + cc];
                float e0 = lrow[cc];
                eb[cc] = silu_f(np + e0 + t1[cc] * t2[cc]);
            }
        }
    }

    // esym -> LDS
    #pragma unroll
    for (int cc = 0; cc < OC; ++cc) lrow[cc] = ea[cc] + eb[cc];

    // eo1 + LayerNorm (lane-local over 32) + silu + eo2
    float y[32];
    #pragma unroll
    for (int cc = 0; cc < 32; ++cc) y[cc] = b_eo1[cc];
    gemv_lds<64, 32>(W_eo1, lrow, y);

    float mean = 0.f;
    #pragma unroll
    for (int cc = 0; cc < 32; ++cc) mean += y[cc];
    mean *= (1.0f / 32.0f);
    float var = 0.f;
    #pragma unroll
    for (int cc = 0; cc < 32; ++cc) { float dd = y[cc] - mean; var += dd * dd; }
    var *= (1.0f / 32.0f);
    float rs = rsqrtf(var + 1e-5f);

    float z[32];
    #pragma unroll
    for (int cc = 0; cc < 32; ++cc)
        z[cc] = silu_f((y[cc] - mean) * rs * g_eo[cc] + be_eo[cc]);

    float o[5];
    #pragma unroll
    for (int q = 0; q < 5; ++q) o[q] = b_eo2[q];
    #pragma unroll
    for (int cc = 0; cc < 32; ++cc) {
        #pragma unroll
        for (int q = 0; q < 5; ++q) o[q] += z[cc] * W_eo2[cc * 5 + q];
    }

    if (valid) {
        float* oe1 = out_edge + (((size_t)(b * NQ) + i) * NQ + j) * 5;
        float* oe2 = out_edge + (((size_t)(b * NQ) + j) * NQ + i) * 5;
        #pragma unroll
        for (int q = 0; q < 5; ++q) {
            float v = em ? o[q] : 0.0f;
            oe1[q] = v;
            oe2[q] = v;
        }
    }
}

extern "C" void kernel_launch(void* const* d_in, const int* in_sizes, int n_in,
                              void* d_out, int out_size, void* d_ws, size_t ws_size,
                              hipStream_t stream) {
    const float* node     = (const float*)d_in[0];
    const float* edge     = (const float*)d_in[1];
    const int*   block_id = (const int*)d_in[2];
    const void*  vm_raw   = d_in[3];
    const float* W_nt  = (const float*)d_in[4];
    const float* b_nt  = (const float*)d_in[5];
    const float* W_n1  = (const float*)d_in[6];
    const float* b_n1  = (const float*)d_in[7];
    const float* W_e1  = (const float*)d_in[8];
    const float* b_e1  = (const float*)d_in[9];
    const float* W_f1  = (const float*)d_in[10];
    const float* b_f1  = (const float*)d_in[11];
    const float* W_f2  = (const float*)d_in[12];
    const float* b_f2  = (const float*)d_in[13];
    const float* W_no1 = (const float*)d_in[14];
    const float* b_no1 = (const float*)d_in[15];
    const float* g_no  = (const float*)d_in[16];
    const float* be_no = (const float*)d_in[17];
    const float* W_no2 = (const float*)d_in[18];
    const float* b_no2 = (const float*)d_in[19];
    const float* W_eo1 = (const float*)d_in[20];
    const float* b_eo1 = (const float*)d_in[21];
    const float* g_eo  = (const float*)d_in[22];
    const float* be_eo = (const float*)d_in[23];
    const float* W_eo2 = (const float*)d_in[24];
    const float* b_eo2 = (const float*)d_in[25];

    int*   vmd  = (int*)d_ws;
    float* n_ws = (float*)((char*)d_ws + 8192);
    float* out_node = (float*)d_out;
    float* out_edge = out_node + 4 * 512 * 10;

    decode_mask_kernel<<<1, 256, 0, stream>>>((const unsigned char*)vm_raw, vmd, 4 * 512);
    node_kernel<<<4 * 512, 128, 0, stream>>>(
        node, edge, block_id, vmd,
        W_nt, b_nt, W_n1, b_n1, W_no1, b_no1, g_no, be_no, W_no2, b_no2,
        n_ws, out_node);
    edge_kernel<<<(4 * 512 * 257) / 128, 128, 0, stream>>>(
        edge, block_id, vmd, n_ws,
        W_e1, b_e1, W_f1, b_f1, W_f2, b_f2,
        W_eo1, b_eo1, g_eo, be_eo, W_eo2, b_eo2, out_edge);
}